// Round 1
// baseline (3077.461 us; speedup 1.0000x reference)
//
#include <hip/hip_runtime.h>
#include <math.h>

#define IN_DIM 128
#define HID 64
#define OUT_DIM 128
constexpr float EPS = 1e-5f;

// ---------------------------------------------------------------------------
// ws layout (floats):
//   [0,128)    column sums
//   [128,256)  column sum-of-squares
//   [256,384)  scale  = gamma * rsqrt(var+eps)
//   [384,512)  shift  = beta - mean*scale
//   [512, 512+N)            s[dst] softmax denominators
//   then q[N*64], k[N*64], v[N*128], ex[E]
// ---------------------------------------------------------------------------

__global__ __launch_bounds__(256) void stats_kernel(
    const float* __restrict__ feat, float* __restrict__ ws, int n_nodes)
{
    int col  = threadIdx.x & 127;
    int half = threadIdx.x >> 7;
    float sum = 0.f, sq = 0.f;
    for (int r = blockIdx.x * 2 + half; r < n_nodes; r += gridDim.x * 2) {
        float x = feat[r * IN_DIM + col];
        sum += x; sq += x * x;
    }
    __shared__ float redS[256], redQ[256];
    redS[threadIdx.x] = sum; redQ[threadIdx.x] = sq;
    __syncthreads();
    if (threadIdx.x < 128) {
        sum = redS[threadIdx.x] + redS[threadIdx.x + 128];
        sq  = redQ[threadIdx.x] + redQ[threadIdx.x + 128];
        unsafeAtomicAdd(&ws[col], sum);
        unsafeAtomicAdd(&ws[128 + col], sq);
    }
}

__global__ void finalize_stats(
    const float* __restrict__ gamma, const float* __restrict__ beta,
    float* __restrict__ ws, int n_nodes)
{
    int j = threadIdx.x;  // 128 threads
    float inv_n = 1.0f / (float)n_nodes;
    float mean = ws[j] * inv_n;
    float var  = ws[128 + j] * inv_n - mean * mean;
    float sc   = gamma[j] * rsqrtf(var + EPS);
    ws[256 + j] = sc;
    ws[384 + j] = beta[j] - mean * sc;
}

// Fused layernorm + GEMM producing q (with bias), k, v.
// grid: (ceil(N/64), 4)  blockIdx.y: 0=q, 1=k, 2=v[:,0:64], 3=v[:,64:128]
__global__ __launch_bounds__(256) void qkv_gemm(
    const float* __restrict__ feat,
    const float* __restrict__ Wq, const float* __restrict__ bq,
    const float* __restrict__ Wk, const float* __restrict__ Wv,
    const float* __restrict__ scale, const float* __restrict__ shift,
    float* __restrict__ q, float* __restrict__ k, float* __restrict__ v,
    int n_nodes)
{
    __shared__ float As[32][64];   // [k][row]
    __shared__ float Bs[32][64];   // [k][col]
    __shared__ float sc[IN_DIM], sh[IN_DIM];

    int tid = threadIdx.x;
    if (tid < IN_DIM) { sc[tid] = scale[tid]; sh[tid] = shift[tid]; }

    int row0 = blockIdx.x * 64;
    int cblk = blockIdx.y;
    const float* Wsrc; int ldB, c0;
    if (cblk == 0)      { Wsrc = Wq; ldB = HID;     c0 = 0;  }
    else if (cblk == 1) { Wsrc = Wk; ldB = HID;     c0 = 0;  }
    else                { Wsrc = Wv; ldB = OUT_DIM; c0 = (cblk - 2) * 64; }

    int tr = tid >> 4;   // 0..15 -> rows tr*4..tr*4+3
    int tc = tid & 15;   // 0..15 -> cols tc*4..tc*4+3
    float acc[4][4] = {};
    __syncthreads();

    for (int kk = 0; kk < IN_DIM; kk += 32) {
        // A tile: 64 rows x 32 k, layernorm applied on load, stored transposed
        #pragma unroll
        for (int i = 0; i < 2; i++) {
            int li = tid + i * 256;          // float4 index 0..511
            int r  = li >> 3;                // 8 float4 per row
            int kc = (li & 7) * 4;
            int row = row0 + r;
            float4 a = make_float4(0.f, 0.f, 0.f, 0.f);
            if (row < n_nodes) a = *(const float4*)&feat[row * IN_DIM + kk + kc];
            a.x = a.x * sc[kk + kc]     + sh[kk + kc];
            a.y = a.y * sc[kk + kc + 1] + sh[kk + kc + 1];
            a.z = a.z * sc[kk + kc + 2] + sh[kk + kc + 2];
            a.w = a.w * sc[kk + kc + 3] + sh[kk + kc + 3];
            As[kc][r] = a.x; As[kc + 1][r] = a.y;
            As[kc + 2][r] = a.z; As[kc + 3][r] = a.w;
        }
        // B tile: 32 k x 64 cols, coalesced
        #pragma unroll
        for (int i = 0; i < 8; i++) {
            int li = i * 256 + tid;
            int kb = li >> 6, cb = li & 63;
            Bs[kb][cb] = Wsrc[(kk + kb) * ldB + c0 + cb];
        }
        __syncthreads();
        #pragma unroll
        for (int kq = 0; kq < 32; kq++) {
            float4 a4 = *(const float4*)&As[kq][tr * 4];
            float4 b4 = *(const float4*)&Bs[kq][tc * 4];
            float av[4] = {a4.x, a4.y, a4.z, a4.w};
            float bv[4] = {b4.x, b4.y, b4.z, b4.w};
            #pragma unroll
            for (int i = 0; i < 4; i++)
                #pragma unroll
                for (int j = 0; j < 4; j++)
                    acc[i][j] += av[i] * bv[j];
        }
        __syncthreads();
    }

    float bias[4] = {0.f, 0.f, 0.f, 0.f};
    float* outp; int ldo, co;
    if (cblk == 0) {
        outp = q; ldo = HID; co = 0;
        #pragma unroll
        for (int j = 0; j < 4; j++) bias[j] = bq[tc * 4 + j];
    } else if (cblk == 1) { outp = k; ldo = HID; co = 0; }
    else                  { outp = v; ldo = OUT_DIM; co = (cblk - 2) * 64; }

    #pragma unroll
    for (int i = 0; i < 4; i++) {
        int row = row0 + tr * 4 + i;
        if (row < n_nodes) {
            float4 o = make_float4(acc[i][0] + bias[0], acc[i][1] + bias[1],
                                   acc[i][2] + bias[2], acc[i][3] + bias[3]);
            *(float4*)&outp[row * ldo + co + tc * 4] = o;
        }
    }
}

// 16 lanes per edge: e = sum_j We[j]*sigmoid(q[src][j]+k[dst][j]);
// ex[e]=exp(e); s[dst]+=ex  (max-subtraction dropped: |e| <= ||We||_1 ~ 3)
__global__ __launch_bounds__(256) void edge_logits(
    const int* __restrict__ src, const int* __restrict__ dst,
    const float* __restrict__ q, const float* __restrict__ k,
    const float* __restrict__ We,
    float* __restrict__ ex, float* __restrict__ s, int n_edges)
{
    int gtid = blockIdx.x * 256 + threadIdx.x;
    int e    = gtid >> 4;          // 16 lanes per edge
    int sub  = gtid & 15;
    if (e >= n_edges) return;
    int sN = src[e], dN = dst[e];
    float4 qv = *(const float4*)&q[sN * HID + sub * 4];
    float4 kv = *(const float4*)&k[dN * HID + sub * 4];
    float4 wv = *(const float4*)&We[sub * 4];
    float t = 0.f;
    t += wv.x / (1.f + __expf(-(qv.x + kv.x)));
    t += wv.y / (1.f + __expf(-(qv.y + kv.y)));
    t += wv.z / (1.f + __expf(-(qv.z + kv.z)));
    t += wv.w / (1.f + __expf(-(qv.w + kv.w)));
    t += __shfl_xor(t, 8);
    t += __shfl_xor(t, 4);
    t += __shfl_xor(t, 2);
    t += __shfl_xor(t, 1);
    if (sub == 0) {
        float exv = __expf(t);
        ex[e] = exv;
        unsafeAtomicAdd(&s[dN], exv);
    }
}

// 32 lanes per edge: rst[dst] += (ex/s[dst]) * v[src]
__global__ __launch_bounds__(256) void edge_scatter(
    const int* __restrict__ src, const int* __restrict__ dst,
    const float* __restrict__ v, const float* __restrict__ ex,
    const float* __restrict__ s, float* __restrict__ out, int n_edges)
{
    long long gtid = (long long)blockIdx.x * 256 + threadIdx.x;
    int e   = (int)(gtid >> 5);     // 32 lanes per edge
    int sub = (int)(gtid & 31);
    if (e >= n_edges) return;
    int sN = src[e], dN = dst[e];
    float a = ex[e] / s[dN];
    float4 vv = *(const float4*)&v[sN * OUT_DIM + sub * 4];
    float* o = &out[dN * OUT_DIM + sub * 4];
    unsafeAtomicAdd(o + 0, a * vv.x);
    unsafeAtomicAdd(o + 1, a * vv.y);
    unsafeAtomicAdd(o + 2, a * vv.z);
    unsafeAtomicAdd(o + 3, a * vv.w);
}

extern "C" void kernel_launch(void* const* d_in, const int* in_sizes, int n_in,
                              void* d_out, int out_size, void* d_ws, size_t ws_size,
                              hipStream_t stream)
{
    const float* feat  = (const float*)d_in[0];
    const int*   src   = (const int*)d_in[1];
    const int*   dst   = (const int*)d_in[2];
    const float* gamma = (const float*)d_in[3];
    const float* beta  = (const float*)d_in[4];
    const float* Wq    = (const float*)d_in[5];
    const float* bq    = (const float*)d_in[6];
    const float* Wk    = (const float*)d_in[7];
    const float* Wv    = (const float*)d_in[8];
    const float* We    = (const float*)d_in[9];

    int n_nodes = in_sizes[0] / IN_DIM;
    int n_edges = in_sizes[1];

    float* ws    = (float*)d_ws;
    float* scale = ws + 256;
    float* shift = ws + 384;
    float* s     = ws + 512;
    float* q     = s + n_nodes;
    float* k     = q + (size_t)n_nodes * HID;
    float* v     = k + (size_t)n_nodes * HID;
    float* ex    = v + (size_t)n_nodes * OUT_DIM;

    // zero stats + s, and the output accumulator
    hipMemsetAsync(ws, 0, (512 + (size_t)n_nodes) * sizeof(float), stream);
    hipMemsetAsync(d_out, 0, (size_t)out_size * sizeof(float), stream);

    stats_kernel<<<256, 256, 0, stream>>>(feat, ws, n_nodes);
    finalize_stats<<<1, 128, 0, stream>>>(gamma, beta, ws, n_nodes);

    dim3 gemm_grid((n_nodes + 63) / 64, 4);
    qkv_gemm<<<gemm_grid, 256, 0, stream>>>(feat, Wq, bq, Wk, Wv,
                                            scale, shift, q, k, v, n_nodes);

    long long lg_threads = (long long)n_edges * 16;
    edge_logits<<<(int)((lg_threads + 255) / 256), 256, 0, stream>>>(
        src, dst, q, k, We, ex, s, n_edges);

    long long sc_threads = (long long)n_edges * 32;
    edge_scatter<<<(int)((sc_threads + 255) / 256), 256, 0, stream>>>(
        src, dst, v, ex, s, (float*)d_out, n_edges);
}

// Round 2
// 909.064 us; speedup vs baseline: 3.3853x; 3.3853x over previous
//
#include <hip/hip_runtime.h>
#include <math.h>

#define IN_DIM 128
#define HID 64
#define OUT_DIM 128
constexpr float EPS = 1e-5f;

// ---------------------------------------------------------------------------
// ws layout:
//   float [0,128)   column sums
//   float [128,256) column sum-of-squares
//   float [256,384) scale = gamma*rsqrt(var+eps)
//   float [384,512) shift = beta - mean*scale
//   int   deg[N], offsets[N+1], cursor[N], csr_src[E]
//   float q[N*64], k[N*64], v[N*128]
// ---------------------------------------------------------------------------

__global__ __launch_bounds__(256) void stats_kernel(
    const float* __restrict__ feat, float* __restrict__ ws, int n_nodes)
{
    int col  = threadIdx.x & 127;
    int half = threadIdx.x >> 7;
    float sum = 0.f, sq = 0.f;
    for (int r = blockIdx.x * 2 + half; r < n_nodes; r += gridDim.x * 2) {
        float x = feat[r * IN_DIM + col];
        sum += x; sq += x * x;
    }
    __shared__ float redS[256], redQ[256];
    redS[threadIdx.x] = sum; redQ[threadIdx.x] = sq;
    __syncthreads();
    if (threadIdx.x < 128) {
        sum = redS[threadIdx.x] + redS[threadIdx.x + 128];
        sq  = redQ[threadIdx.x] + redQ[threadIdx.x + 128];
        unsafeAtomicAdd(&ws[col], sum);
        unsafeAtomicAdd(&ws[128 + col], sq);
    }
}

__global__ void finalize_stats(
    const float* __restrict__ gamma, const float* __restrict__ beta,
    float* __restrict__ ws, int n_nodes)
{
    int j = threadIdx.x;  // 128 threads
    float inv_n = 1.0f / (float)n_nodes;
    float mean = ws[j] * inv_n;
    float var  = ws[128 + j] * inv_n - mean * mean;
    float sc   = gamma[j] * rsqrtf(var + EPS);
    ws[256 + j] = sc;
    ws[384 + j] = beta[j] - mean * sc;
}

// Fused layernorm + GEMM producing q (with bias), k, v.
// grid: (ceil(N/64), 4)  blockIdx.y: 0=q, 1=k, 2=v[:,0:64], 3=v[:,64:128]
__global__ __launch_bounds__(256) void qkv_gemm(
    const float* __restrict__ feat,
    const float* __restrict__ Wq, const float* __restrict__ bq,
    const float* __restrict__ Wk, const float* __restrict__ Wv,
    const float* __restrict__ scale, const float* __restrict__ shift,
    float* __restrict__ q, float* __restrict__ k, float* __restrict__ v,
    int n_nodes)
{
    __shared__ float As[32][64];   // [k][row]
    __shared__ float Bs[32][64];   // [k][col]
    __shared__ float sc[IN_DIM], sh[IN_DIM];

    int tid = threadIdx.x;
    if (tid < IN_DIM) { sc[tid] = scale[tid]; sh[tid] = shift[tid]; }

    int row0 = blockIdx.x * 64;
    int cblk = blockIdx.y;
    const float* Wsrc; int ldB, c0;
    if (cblk == 0)      { Wsrc = Wq; ldB = HID;     c0 = 0;  }
    else if (cblk == 1) { Wsrc = Wk; ldB = HID;     c0 = 0;  }
    else                { Wsrc = Wv; ldB = OUT_DIM; c0 = (cblk - 2) * 64; }

    int tr = tid >> 4;
    int tc = tid & 15;
    float acc[4][4] = {};
    __syncthreads();

    for (int kk = 0; kk < IN_DIM; kk += 32) {
        #pragma unroll
        for (int i = 0; i < 2; i++) {
            int li = tid + i * 256;
            int r  = li >> 3;
            int kc = (li & 7) * 4;
            int row = row0 + r;
            float4 a = make_float4(0.f, 0.f, 0.f, 0.f);
            if (row < n_nodes) a = *(const float4*)&feat[row * IN_DIM + kk + kc];
            a.x = a.x * sc[kk + kc]     + sh[kk + kc];
            a.y = a.y * sc[kk + kc + 1] + sh[kk + kc + 1];
            a.z = a.z * sc[kk + kc + 2] + sh[kk + kc + 2];
            a.w = a.w * sc[kk + kc + 3] + sh[kk + kc + 3];
            As[kc][r] = a.x; As[kc + 1][r] = a.y;
            As[kc + 2][r] = a.z; As[kc + 3][r] = a.w;
        }
        #pragma unroll
        for (int i = 0; i < 8; i++) {
            int li = i * 256 + tid;
            int kb = li >> 6, cb = li & 63;
            Bs[kb][cb] = Wsrc[(kk + kb) * ldB + c0 + cb];
        }
        __syncthreads();
        #pragma unroll
        for (int kq = 0; kq < 32; kq++) {
            float4 a4 = *(const float4*)&As[kq][tr * 4];
            float4 b4 = *(const float4*)&Bs[kq][tc * 4];
            float av[4] = {a4.x, a4.y, a4.z, a4.w};
            float bv[4] = {b4.x, b4.y, b4.z, b4.w};
            #pragma unroll
            for (int i = 0; i < 4; i++)
                #pragma unroll
                for (int j = 0; j < 4; j++)
                    acc[i][j] += av[i] * bv[j];
        }
        __syncthreads();
    }

    float bias[4] = {0.f, 0.f, 0.f, 0.f};
    float* outp; int ldo, co;
    if (cblk == 0) {
        outp = q; ldo = HID; co = 0;
        #pragma unroll
        for (int j = 0; j < 4; j++) bias[j] = bq[tc * 4 + j];
    } else if (cblk == 1) { outp = k; ldo = HID; co = 0; }
    else                  { outp = v; ldo = OUT_DIM; co = (cblk - 2) * 64; }

    #pragma unroll
    for (int i = 0; i < 4; i++) {
        int row = row0 + tr * 4 + i;
        if (row < n_nodes) {
            float4 o = make_float4(acc[i][0] + bias[0], acc[i][1] + bias[1],
                                   acc[i][2] + bias[2], acc[i][3] + bias[3]);
            *(float4*)&outp[row * ldo + co + tc * 4] = o;
        }
    }
}

// ---------------- CSR build: histogram -> scan -> fill ----------------

__global__ __launch_bounds__(256) void hist_kernel(
    const int* __restrict__ dst, int* __restrict__ deg, int n_edges)
{
    int e = blockIdx.x * 256 + threadIdx.x;
    if (e < n_edges) atomicAdd(&deg[dst[e]], 1);
}

// single block, 1024 threads: exclusive scan of deg[n] -> offsets[n+1], cursor[n]
__global__ __launch_bounds__(1024) void scan_kernel(
    const int* __restrict__ deg, int* __restrict__ offsets,
    int* __restrict__ cursor, int n)
{
    __shared__ int part[1024];
    int t = threadIdx.x;
    int chunk = (n + 1023) / 1024;
    int lo = t * chunk;
    int hi = lo + chunk; if (hi > n) hi = n; if (lo > n) lo = n;
    int sum = 0;
    for (int i = lo; i < hi; i++) sum += deg[i];
    part[t] = sum;
    __syncthreads();
    for (int d = 1; d < 1024; d <<= 1) {
        int v = part[t];
        int add = (t >= d) ? part[t - d] : 0;
        __syncthreads();
        part[t] = v + add;
        __syncthreads();
    }
    int off = part[t] - sum;   // exclusive prefix of this chunk
    for (int i = lo; i < hi; i++) {
        offsets[i] = off; cursor[i] = off;
        off += deg[i];
    }
    if (t == 0) offsets[n] = part[1023];
}

__global__ __launch_bounds__(256) void fill_kernel(
    const int* __restrict__ src, const int* __restrict__ dst,
    int* __restrict__ cursor, int* __restrict__ csr_src, int n_edges)
{
    int e = blockIdx.x * 256 + threadIdx.x;
    if (e < n_edges) {
        int d = dst[e];
        int pos = atomicAdd(&cursor[d], 1);
        csr_src[pos] = src[e];
    }
}

// ---------------- fused per-node gather: softmax + weighted sum --------
// one wave (64 lanes) per node. lane j owns hid dim j and out dims j, j+64.
__global__ __launch_bounds__(256) void node_gather(
    const int* __restrict__ offsets, const int* __restrict__ csr_src,
    const float* __restrict__ q, const float* __restrict__ k,
    const float* __restrict__ v, const float* __restrict__ We,
    float* __restrict__ out, int n_nodes)
{
    int node = (blockIdx.x * 256 + threadIdx.x) >> 6;
    int lane = threadIdx.x & 63;
    if (node >= n_nodes) return;

    int beg = offsets[node];
    int end = offsets[node + 1];
    float kd = k[node * HID + lane];
    float we = We[lane];

    float acc0 = 0.f, acc1 = 0.f, ssum = 0.f;
    for (int p = beg; p < end; p++) {
        int sN = csr_src[p];                  // wave-uniform
        float qv = q[sN * HID + lane];
        float t  = we / (1.f + __expf(-(qv + kd)));
        t += __shfl_xor(t, 32);
        t += __shfl_xor(t, 16);
        t += __shfl_xor(t, 8);
        t += __shfl_xor(t, 4);
        t += __shfl_xor(t, 2);
        t += __shfl_xor(t, 1);
        float exv = __expf(t);
        ssum += exv;
        acc0 += exv * v[sN * OUT_DIM + lane];
        acc1 += exv * v[sN * OUT_DIM + 64 + lane];
    }
    float inv = (ssum > 0.f) ? 1.f / ssum : 0.f;
    out[node * OUT_DIM + lane]      = acc0 * inv;
    out[node * OUT_DIM + 64 + lane] = acc1 * inv;
}

extern "C" void kernel_launch(void* const* d_in, const int* in_sizes, int n_in,
                              void* d_out, int out_size, void* d_ws, size_t ws_size,
                              hipStream_t stream)
{
    const float* feat  = (const float*)d_in[0];
    const int*   src   = (const int*)d_in[1];
    const int*   dst   = (const int*)d_in[2];
    const float* gamma = (const float*)d_in[3];
    const float* beta  = (const float*)d_in[4];
    const float* Wq    = (const float*)d_in[5];
    const float* bq    = (const float*)d_in[6];
    const float* Wk    = (const float*)d_in[7];
    const float* Wv    = (const float*)d_in[8];
    const float* We    = (const float*)d_in[9];

    int n_nodes = in_sizes[0] / IN_DIM;
    int n_edges = in_sizes[1];

    float* ws      = (float*)d_ws;
    float* scale   = ws + 256;
    float* shift   = ws + 384;
    int*   deg     = (int*)(ws + 512);
    int*   offsets = deg + n_nodes;
    int*   cursor  = offsets + n_nodes + 1;
    int*   csr_src = cursor + n_nodes;
    float* q       = (float*)(csr_src + n_edges);
    float* k       = q + (size_t)n_nodes * HID;
    float* v       = k + (size_t)n_nodes * HID;

    // zero stats + deg histogram (contiguous region)
    hipMemsetAsync(ws, 0, (512 + (size_t)n_nodes) * sizeof(float), stream);

    stats_kernel<<<256, 256, 0, stream>>>(feat, ws, n_nodes);
    finalize_stats<<<1, 128, 0, stream>>>(gamma, beta, ws, n_nodes);

    dim3 gemm_grid((n_nodes + 63) / 64, 4);
    qkv_gemm<<<gemm_grid, 256, 0, stream>>>(feat, Wq, bq, Wk, Wv,
                                            scale, shift, q, k, v, n_nodes);

    int eb = (n_edges + 255) / 256;
    hist_kernel<<<eb, 256, 0, stream>>>(dst, deg, n_edges);
    scan_kernel<<<1, 1024, 0, stream>>>(deg, offsets, cursor, n_nodes);
    fill_kernel<<<eb, 256, 0, stream>>>(src, dst, cursor, csr_src, n_edges);

    long long g_threads = (long long)n_nodes * 64;
    node_gather<<<(int)((g_threads + 255) / 256), 256, 0, stream>>>(
        offsets, csr_src, q, k, v, We, (float*)d_out, n_nodes);
}

// Round 3
// 781.832 us; speedup vs baseline: 3.9362x; 1.1627x over previous
//
#include <hip/hip_runtime.h>
#include <math.h>

#define IN_DIM 128
#define HID 64
#define OUT_DIM 128
constexpr float EPS = 1e-5f;

// ---------------------------------------------------------------------------
// ws layout:
//   float [0,128)   column sums
//   float [128,256) column sum-of-squares
//   float [256,384) scale = gamma*rsqrt(var+eps)
//   float [384,512) shift = beta - mean*scale
//   int   deg[N], offsets[N+1], cursor[N], part[256], csr_src[E]
//   float q[N*64], k[N*64], v[N*128]   (16B-aligned)
// ---------------------------------------------------------------------------

__global__ __launch_bounds__(256) void stats_kernel(
    const float* __restrict__ feat, float* __restrict__ ws, int n_nodes)
{
    int col  = threadIdx.x & 127;
    int half = threadIdx.x >> 7;
    float sum = 0.f, sq = 0.f;
    for (int r = blockIdx.x * 2 + half; r < n_nodes; r += gridDim.x * 2) {
        float x = feat[r * IN_DIM + col];
        sum += x; sq += x * x;
    }
    __shared__ float redS[256], redQ[256];
    redS[threadIdx.x] = sum; redQ[threadIdx.x] = sq;
    __syncthreads();
    if (threadIdx.x < 128) {
        sum = redS[threadIdx.x] + redS[threadIdx.x + 128];
        sq  = redQ[threadIdx.x] + redQ[threadIdx.x + 128];
        unsafeAtomicAdd(&ws[col], sum);
        unsafeAtomicAdd(&ws[128 + col], sq);
    }
}

__global__ void finalize_stats(
    const float* __restrict__ gamma, const float* __restrict__ beta,
    float* __restrict__ ws, int n_nodes)
{
    int j = threadIdx.x;  // 128 threads
    float inv_n = 1.0f / (float)n_nodes;
    float mean = ws[j] * inv_n;
    float var  = ws[128 + j] * inv_n - mean * mean;
    float sc   = gamma[j] * rsqrtf(var + EPS);
    ws[256 + j] = sc;
    ws[384 + j] = beta[j] - mean * sc;
}

// Fused layernorm + GEMM: one 64-row tile computes all 256 output cols
// cols [0,64)=q (+bias), [64,128)=k, [128,256)=v.  8x8 acc per thread.
__global__ __launch_bounds__(256) void qkv_gemm(
    const float* __restrict__ feat,
    const float* __restrict__ Wq, const float* __restrict__ bq,
    const float* __restrict__ Wk, const float* __restrict__ Wv,
    const float* __restrict__ scale, const float* __restrict__ shift,
    float* __restrict__ q, float* __restrict__ k, float* __restrict__ v,
    int n_nodes)
{
    __shared__ float As[32][68];    // [k][row], pad 68 keeps 16B align, <=4-way wr conflict
    __shared__ float Bs[32][256];   // [k][col]
    __shared__ float sc[IN_DIM], sh[IN_DIM];

    int tid = threadIdx.x;
    if (tid < IN_DIM) { sc[tid] = scale[tid]; sh[tid] = shift[tid]; }

    int row0 = blockIdx.x * 64;
    int tr = tid >> 5;   // 0..7  -> rows tr*8 .. tr*8+7
    int tc = tid & 31;   // 0..31 -> cols tc*8 .. tc*8+7
    float acc[8][8] = {};
    __syncthreads();

    for (int kk = 0; kk < IN_DIM; kk += 32) {
        // A tile: 64 rows x 32 k, layernorm on load, transposed store
        #pragma unroll
        for (int i = 0; i < 2; i++) {
            int li = tid + i * 256;          // 0..511 float4 slots
            int r  = li >> 3;                // 64 rows
            int kc = (li & 7) * 4;           // 8 float4 per row
            int row = row0 + r;
            float4 a = make_float4(0.f, 0.f, 0.f, 0.f);
            if (row < n_nodes) a = *(const float4*)&feat[row * IN_DIM + kk + kc];
            a.x = a.x * sc[kk + kc]     + sh[kk + kc];
            a.y = a.y * sc[kk + kc + 1] + sh[kk + kc + 1];
            a.z = a.z * sc[kk + kc + 2] + sh[kk + kc + 2];
            a.w = a.w * sc[kk + kc + 3] + sh[kk + kc + 3];
            As[kc][r] = a.x; As[kc + 1][r] = a.y;
            As[kc + 2][r] = a.z; As[kc + 3][r] = a.w;
        }
        // B tile: 32 k x 256 cols from [Wq|Wk|Wv], 8 float4 per thread
        #pragma unroll
        for (int i = 0; i < 8; i++) {
            int li = i * 256 + tid;          // 0..2047
            int kb = li >> 6;                // 0..31
            int c  = (li & 63) * 4;          // 0..252
            int kglob = kk + kb;
            const float* srcp;
            if (c < 64)       srcp = &Wq[kglob * HID + c];
            else if (c < 128) srcp = &Wk[kglob * HID + (c - 64)];
            else              srcp = &Wv[kglob * OUT_DIM + (c - 128)];
            *(float4*)&Bs[kb][c] = *(const float4*)srcp;
        }
        __syncthreads();
        #pragma unroll
        for (int kq = 0; kq < 32; kq++) {
            float4 a0 = *(const float4*)&As[kq][tr * 8];
            float4 a1 = *(const float4*)&As[kq][tr * 8 + 4];
            float4 b0 = *(const float4*)&Bs[kq][tc * 8];
            float4 b1 = *(const float4*)&Bs[kq][tc * 8 + 4];
            float av[8] = {a0.x, a0.y, a0.z, a0.w, a1.x, a1.y, a1.z, a1.w};
            float bv[8] = {b0.x, b0.y, b0.z, b0.w, b1.x, b1.y, b1.z, b1.w};
            #pragma unroll
            for (int i = 0; i < 8; i++)
                #pragma unroll
                for (int j = 0; j < 8; j++)
                    acc[i][j] += av[i] * bv[j];
        }
        __syncthreads();
    }

    // epilogue: each thread's 8 cols live entirely in one of q/k/v
    float bias[8] = {0,0,0,0,0,0,0,0};
    float* outp; int ldo, c0;
    if (tc < 8) {
        outp = q; ldo = HID; c0 = tc * 8;
        #pragma unroll
        for (int j = 0; j < 8; j++) bias[j] = bq[c0 + j];
    } else if (tc < 16) { outp = k; ldo = HID;     c0 = tc * 8 - 64; }
    else               { outp = v; ldo = OUT_DIM; c0 = tc * 8 - 128; }

    #pragma unroll
    for (int i = 0; i < 8; i++) {
        int row = row0 + tr * 8 + i;
        if (row < n_nodes) {
            float4 o0 = make_float4(acc[i][0]+bias[0], acc[i][1]+bias[1],
                                    acc[i][2]+bias[2], acc[i][3]+bias[3]);
            float4 o1 = make_float4(acc[i][4]+bias[4], acc[i][5]+bias[5],
                                    acc[i][6]+bias[6], acc[i][7]+bias[7]);
            *(float4*)&outp[row * ldo + c0]     = o0;
            *(float4*)&outp[row * ldo + c0 + 4] = o1;
        }
    }
}

// ---------------- CSR build: histogram -> hierarchical scan -> fill ----

__global__ __launch_bounds__(256) void hist_kernel(
    const int* __restrict__ dst, int* __restrict__ deg, int n_edges)
{
    int e = blockIdx.x * 256 + threadIdx.x;
    if (e < n_edges) atomicAdd(&deg[dst[e]], 1);
}

#define SCAN_B 256

__global__ __launch_bounds__(256) void scan_partial(
    const int* __restrict__ deg, int* __restrict__ part, int n)
{
    int chunk = (n + SCAN_B - 1) / SCAN_B;
    int lo = blockIdx.x * chunk;
    int hi = lo + chunk; if (hi > n) hi = n;
    int s = 0;
    for (int i = lo + threadIdx.x; i < hi; i += 256) s += deg[i];
    __shared__ int red[256];
    red[threadIdx.x] = s; __syncthreads();
    for (int d = 128; d; d >>= 1) {
        if (threadIdx.x < d) red[threadIdx.x] += red[threadIdx.x + d];
        __syncthreads();
    }
    if (threadIdx.x == 0) part[blockIdx.x] = red[0];
}

__global__ __launch_bounds__(256) void scan_combine(
    int* __restrict__ part, int* __restrict__ offsets, int n)
{
    __shared__ int tmp[256];
    int t = threadIdx.x;
    int v = part[t];
    tmp[t] = v; __syncthreads();
    for (int d = 1; d < 256; d <<= 1) {
        int cur = tmp[t];
        int add = (t >= d) ? tmp[t - d] : 0;
        __syncthreads();
        tmp[t] = cur + add;
        __syncthreads();
    }
    part[t] = tmp[t] - v;                  // exclusive
    if (t == 255) offsets[n] = tmp[255];
}

__global__ __launch_bounds__(256) void scan_final(
    const int* __restrict__ deg, const int* __restrict__ part,
    int* __restrict__ offsets, int* __restrict__ cursor, int n)
{
    __shared__ int tmp[256];
    int t = threadIdx.x;
    int chunk = (n + SCAN_B - 1) / SCAN_B;
    int lo = blockIdx.x * chunk;
    int hi = lo + chunk; if (hi > n) hi = n;
    int base = part[blockIdx.x];
    for (int i0 = lo; i0 < hi; i0 += 256) {
        int i = i0 + t;
        int d = (i < hi) ? deg[i] : 0;
        tmp[t] = d; __syncthreads();
        for (int s = 1; s < 256; s <<= 1) {
            int cur = tmp[t];
            int add = (t >= s) ? tmp[t - s] : 0;
            __syncthreads();
            tmp[t] = cur + add;
            __syncthreads();
        }
        int excl = tmp[t] - d;
        int total = tmp[255];
        if (i < hi) { offsets[i] = base + excl; cursor[i] = base + excl; }
        base += total;
        __syncthreads();
    }
}

__global__ __launch_bounds__(256) void fill_kernel(
    const int* __restrict__ src, const int* __restrict__ dst,
    int* __restrict__ cursor, int* __restrict__ csr_src, int n_edges)
{
    int e = blockIdx.x * 256 + threadIdx.x;
    if (e < n_edges) {
        int d = dst[e];
        int pos = atomicAdd(&cursor[d], 1);
        csr_src[pos] = src[e];
    }
}

// ---------------- fused per-node gather: softmax + weighted sum --------
// one wave per node; two edges in flight (half-wave per edge, 2 dims/lane)
__global__ __launch_bounds__(256) void node_gather(
    const int* __restrict__ offsets, const int* __restrict__ csr_src,
    const float* __restrict__ q, const float* __restrict__ k,
    const float* __restrict__ v, const float* __restrict__ We,
    float* __restrict__ out, int n_nodes)
{
    int node = (blockIdx.x * 256 + threadIdx.x) >> 6;
    int lane = threadIdx.x & 63;
    if (node >= n_nodes) return;
    int h    = lane & 31;    // dim pair index within half
    int half = lane >> 5;    // which edge of the pair

    int beg = offsets[node];
    int end = offsets[node + 1];
    float2 kd = *(const float2*)&k[node * HID + 2 * h];
    float2 we = *(const float2*)&We[2 * h];

    float a0x = 0.f, a0y = 0.f, a1x = 0.f, a1y = 0.f, ssum = 0.f;
    for (int p = beg + half; p < end; p += 2) {
        int sN = csr_src[p];                        // uniform per half-wave
        float2 qv = *(const float2*)&q[sN * HID + 2 * h];
        float t = we.x * __fdividef(1.f, 1.f + __expf(-(qv.x + kd.x)))
                + we.y * __fdividef(1.f, 1.f + __expf(-(qv.y + kd.y)));
        t += __shfl_xor(t, 16);
        t += __shfl_xor(t, 8);
        t += __shfl_xor(t, 4);
        t += __shfl_xor(t, 2);
        t += __shfl_xor(t, 1);
        float exv = __expf(t);
        ssum += exv;
        float2 v0 = *(const float2*)&v[sN * OUT_DIM + 2 * h];
        float2 v1 = *(const float2*)&v[sN * OUT_DIM + 64 + 2 * h];
        a0x += exv * v0.x; a0y += exv * v0.y;
        a1x += exv * v1.x; a1y += exv * v1.y;
    }
    // combine the two halves
    ssum += __shfl_xor(ssum, 32);
    a0x += __shfl_xor(a0x, 32); a0y += __shfl_xor(a0y, 32);
    a1x += __shfl_xor(a1x, 32); a1y += __shfl_xor(a1y, 32);
    if (half == 0) {
        float inv = (ssum > 0.f) ? __fdividef(1.f, ssum) : 0.f;
        *(float2*)&out[node * OUT_DIM + 2 * h]      = make_float2(a0x * inv, a0y * inv);
        *(float2*)&out[node * OUT_DIM + 64 + 2 * h] = make_float2(a1x * inv, a1y * inv);
    }
}

extern "C" void kernel_launch(void* const* d_in, const int* in_sizes, int n_in,
                              void* d_out, int out_size, void* d_ws, size_t ws_size,
                              hipStream_t stream)
{
    const float* feat  = (const float*)d_in[0];
    const int*   src   = (const int*)d_in[1];
    const int*   dst   = (const int*)d_in[2];
    const float* gamma = (const float*)d_in[3];
    const float* beta  = (const float*)d_in[4];
    const float* Wq    = (const float*)d_in[5];
    const float* bq    = (const float*)d_in[6];
    const float* Wk    = (const float*)d_in[7];
    const float* Wv    = (const float*)d_in[8];
    const float* We    = (const float*)d_in[9];

    int n_nodes = in_sizes[0] / IN_DIM;
    int n_edges = in_sizes[1];

    float* ws      = (float*)d_ws;
    float* scale   = ws + 256;
    float* shift   = ws + 384;
    int*   deg     = (int*)(ws + 512);
    int*   offsets = deg + n_nodes;
    int*   cursor  = offsets + n_nodes + 1;
    int*   part    = cursor + n_nodes;
    int*   csr_src = part + SCAN_B;
    size_t qofs    = (size_t)(512 + 3 * n_nodes + 1 + SCAN_B) + (size_t)n_edges;
    qofs = (qofs + 3) & ~(size_t)3;        // 16B-align
    float* q       = ws + qofs;
    float* k       = q + (size_t)n_nodes * HID;
    float* v       = k + (size_t)n_nodes * HID;

    // zero stats + deg histogram (contiguous region)
    hipMemsetAsync(ws, 0, (512 + (size_t)n_nodes) * sizeof(float), stream);

    stats_kernel<<<256, 256, 0, stream>>>(feat, ws, n_nodes);
    finalize_stats<<<1, 128, 0, stream>>>(gamma, beta, ws, n_nodes);

    qkv_gemm<<<(n_nodes + 63) / 64, 256, 0, stream>>>(
        feat, Wq, bq, Wk, Wv, scale, shift, q, k, v, n_nodes);

    int eb = (n_edges + 255) / 256;
    hist_kernel<<<eb, 256, 0, stream>>>(dst, deg, n_edges);
    scan_partial<<<SCAN_B, 256, 0, stream>>>(deg, part, n_nodes);
    scan_combine<<<1, 256, 0, stream>>>(part, offsets, n_nodes);
    scan_final<<<SCAN_B, 256, 0, stream>>>(deg, part, offsets, cursor, n_nodes);
    fill_kernel<<<eb, 256, 0, stream>>>(src, dst, cursor, csr_src, n_edges);

    long long g_threads = (long long)n_nodes * 64;
    node_gather<<<(int)((g_threads + 255) / 256), 256, 0, stream>>>(
        offsets, csr_src, q, k, v, We, (float*)d_out, n_nodes);
}

// Round 4
// 661.691 us; speedup vs baseline: 4.6509x; 1.1816x over previous
//
#include <hip/hip_runtime.h>
#include <math.h>

#define IN_DIM 128
#define HID 64
#define OUT_DIM 128
constexpr float EPS = 1e-5f;

// ---------------------------------------------------------------------------
// ws layout:
//   float [0,128)   column sums
//   float [128,256) column sum-of-squares
//   float [256,384) scale = gamma*rsqrt(var+eps)
//   float [384,512) shift = beta - mean*scale
//   int   deg[N], offsets[N+1], cursor[N], part[256], csr_src[E]
//   bf16  qb[N*64], kb[N*64], vb[N*128]   (16B-aligned, stored as ushort)
// ---------------------------------------------------------------------------

__device__ inline ushort f2bf(float x) {
    union { float f; unsigned u; } c; c.f = x;
    unsigned r = c.u + 0x7FFF + ((c.u >> 16) & 1);   // round-to-nearest-even
    return (ushort)(r >> 16);
}
__device__ inline float bf2f(ushort u) {
    union { unsigned u; float f; } c; c.u = ((unsigned)u) << 16;
    return c.f;
}
__device__ inline float4 bf4_to_f4(ushort4 u) {
    return make_float4(bf2f(u.x), bf2f(u.y), bf2f(u.z), bf2f(u.w));
}

__global__ __launch_bounds__(256) void stats_kernel(
    const float* __restrict__ feat, float* __restrict__ ws, int n_nodes)
{
    int col  = threadIdx.x & 127;
    int half = threadIdx.x >> 7;
    float sum = 0.f, sq = 0.f;
    for (int r = blockIdx.x * 2 + half; r < n_nodes; r += gridDim.x * 2) {
        float x = feat[r * IN_DIM + col];
        sum += x; sq += x * x;
    }
    __shared__ float redS[256], redQ[256];
    redS[threadIdx.x] = sum; redQ[threadIdx.x] = sq;
    __syncthreads();
    if (threadIdx.x < 128) {
        sum = redS[threadIdx.x] + redS[threadIdx.x + 128];
        sq  = redQ[threadIdx.x] + redQ[threadIdx.x + 128];
        unsafeAtomicAdd(&ws[col], sum);
        unsafeAtomicAdd(&ws[128 + col], sq);
    }
}

__global__ void finalize_stats(
    const float* __restrict__ gamma, const float* __restrict__ beta,
    float* __restrict__ ws, int n_nodes)
{
    int j = threadIdx.x;  // 128 threads
    float inv_n = 1.0f / (float)n_nodes;
    float mean = ws[j] * inv_n;
    float var  = ws[128 + j] * inv_n - mean * mean;
    float sc   = gamma[j] * rsqrtf(var + EPS);
    ws[256 + j] = sc;
    ws[384 + j] = beta[j] - mean * sc;
}

// Fused layernorm + GEMM: one 64-row tile computes all 256 output cols
// cols [0,64)=q (+bias), [64,128)=k, [128,256)=v.  8x8 acc, fp32 compute,
// bf16 (RNE) store.
__global__ __launch_bounds__(256) void qkv_gemm(
    const float* __restrict__ feat,
    const float* __restrict__ Wq, const float* __restrict__ bq,
    const float* __restrict__ Wk, const float* __restrict__ Wv,
    const float* __restrict__ scale, const float* __restrict__ shift,
    ushort* __restrict__ qb, ushort* __restrict__ kb, ushort* __restrict__ vb,
    int n_nodes)
{
    __shared__ float As[32][68];
    __shared__ float Bs[32][256];
    __shared__ float sc[IN_DIM], sh[IN_DIM];

    int tid = threadIdx.x;
    if (tid < IN_DIM) { sc[tid] = scale[tid]; sh[tid] = shift[tid]; }

    int row0 = blockIdx.x * 64;
    int tr = tid >> 5;   // 0..7  -> rows tr*8 .. tr*8+7
    int tc = tid & 31;   // 0..31 -> cols tc*8 .. tc*8+7
    float acc[8][8] = {};
    __syncthreads();

    for (int kk = 0; kk < IN_DIM; kk += 32) {
        #pragma unroll
        for (int i = 0; i < 2; i++) {
            int li = tid + i * 256;
            int r  = li >> 3;
            int kc = (li & 7) * 4;
            int row = row0 + r;
            float4 a = make_float4(0.f, 0.f, 0.f, 0.f);
            if (row < n_nodes) a = *(const float4*)&feat[row * IN_DIM + kk + kc];
            a.x = a.x * sc[kk + kc]     + sh[kk + kc];
            a.y = a.y * sc[kk + kc + 1] + sh[kk + kc + 1];
            a.z = a.z * sc[kk + kc + 2] + sh[kk + kc + 2];
            a.w = a.w * sc[kk + kc + 3] + sh[kk + kc + 3];
            As[kc][r] = a.x; As[kc + 1][r] = a.y;
            As[kc + 2][r] = a.z; As[kc + 3][r] = a.w;
        }
        #pragma unroll
        for (int i = 0; i < 8; i++) {
            int li = i * 256 + tid;
            int kb_ = li >> 6;
            int c   = (li & 63) * 4;
            int kglob = kk + kb_;
            const float* srcp;
            if (c < 64)       srcp = &Wq[kglob * HID + c];
            else if (c < 128) srcp = &Wk[kglob * HID + (c - 64)];
            else              srcp = &Wv[kglob * OUT_DIM + (c - 128)];
            *(float4*)&Bs[kb_][c] = *(const float4*)srcp;
        }
        __syncthreads();
        #pragma unroll
        for (int kq = 0; kq < 32; kq++) {
            float4 a0 = *(const float4*)&As[kq][tr * 8];
            float4 a1 = *(const float4*)&As[kq][tr * 8 + 4];
            float4 b0 = *(const float4*)&Bs[kq][tc * 8];
            float4 b1 = *(const float4*)&Bs[kq][tc * 8 + 4];
            float av[8] = {a0.x, a0.y, a0.z, a0.w, a1.x, a1.y, a1.z, a1.w};
            float bv[8] = {b0.x, b0.y, b0.z, b0.w, b1.x, b1.y, b1.z, b1.w};
            #pragma unroll
            for (int i = 0; i < 8; i++)
                #pragma unroll
                for (int j = 0; j < 8; j++)
                    acc[i][j] += av[i] * bv[j];
        }
        __syncthreads();
    }

    float bias[8] = {0,0,0,0,0,0,0,0};
    ushort* outp; int ldo, c0;
    if (tc < 8) {
        outp = qb; ldo = HID; c0 = tc * 8;
        #pragma unroll
        for (int j = 0; j < 8; j++) bias[j] = bq[c0 + j];
    } else if (tc < 16) { outp = kb; ldo = HID;     c0 = tc * 8 - 64; }
    else               { outp = vb; ldo = OUT_DIM; c0 = tc * 8 - 128; }

    #pragma unroll
    for (int i = 0; i < 8; i++) {
        int row = row0 + tr * 8 + i;
        if (row < n_nodes) {
            ushort4 lo, hi;
            lo.x = f2bf(acc[i][0] + bias[0]); lo.y = f2bf(acc[i][1] + bias[1]);
            lo.z = f2bf(acc[i][2] + bias[2]); lo.w = f2bf(acc[i][3] + bias[3]);
            hi.x = f2bf(acc[i][4] + bias[4]); hi.y = f2bf(acc[i][5] + bias[5]);
            hi.z = f2bf(acc[i][6] + bias[6]); hi.w = f2bf(acc[i][7] + bias[7]);
            *(ushort4*)&outp[row * ldo + c0]     = lo;
            *(ushort4*)&outp[row * ldo + c0 + 4] = hi;
        }
    }
}

// ---------------- CSR build: histogram -> hierarchical scan -> fill ----

__global__ __launch_bounds__(256) void hist_kernel(
    const int* __restrict__ dst, int* __restrict__ deg, int n_edges)
{
    int e = blockIdx.x * 256 + threadIdx.x;
    if (e < n_edges) atomicAdd(&deg[dst[e]], 1);
}

#define SCAN_B 256

__global__ __launch_bounds__(256) void scan_partial(
    const int* __restrict__ deg, int* __restrict__ part, int n)
{
    int chunk = (n + SCAN_B - 1) / SCAN_B;
    int lo = blockIdx.x * chunk;
    int hi = lo + chunk; if (hi > n) hi = n;
    int s = 0;
    for (int i = lo + threadIdx.x; i < hi; i += 256) s += deg[i];
    __shared__ int red[256];
    red[threadIdx.x] = s; __syncthreads();
    for (int d = 128; d; d >>= 1) {
        if (threadIdx.x < d) red[threadIdx.x] += red[threadIdx.x + d];
        __syncthreads();
    }
    if (threadIdx.x == 0) part[blockIdx.x] = red[0];
}

__global__ __launch_bounds__(256) void scan_combine(
    int* __restrict__ part, int* __restrict__ offsets, int n)
{
    __shared__ int tmp[256];
    int t = threadIdx.x;
    int v = part[t];
    tmp[t] = v; __syncthreads();
    for (int d = 1; d < 256; d <<= 1) {
        int cur = tmp[t];
        int add = (t >= d) ? tmp[t - d] : 0;
        __syncthreads();
        tmp[t] = cur + add;
        __syncthreads();
    }
    part[t] = tmp[t] - v;                  // exclusive
    if (t == 255) offsets[n] = tmp[255];
}

__global__ __launch_bounds__(256) void scan_final(
    const int* __restrict__ deg, const int* __restrict__ part,
    int* __restrict__ offsets, int* __restrict__ cursor, int n)
{
    __shared__ int tmp[256];
    int t = threadIdx.x;
    int chunk = (n + SCAN_B - 1) / SCAN_B;
    int lo = blockIdx.x * chunk;
    int hi = lo + chunk; if (hi > n) hi = n;
    int base = part[blockIdx.x];
    for (int i0 = lo; i0 < hi; i0 += 256) {
        int i = i0 + t;
        int d = (i < hi) ? deg[i] : 0;
        tmp[t] = d; __syncthreads();
        for (int s = 1; s < 256; s <<= 1) {
            int cur = tmp[t];
            int add = (t >= s) ? tmp[t - s] : 0;
            __syncthreads();
            tmp[t] = cur + add;
            __syncthreads();
        }
        int excl = tmp[t] - d;
        int total = tmp[255];
        if (i < hi) { offsets[i] = base + excl; cursor[i] = base + excl; }
        base += total;
        __syncthreads();
    }
}

__global__ __launch_bounds__(256) void fill_kernel(
    const int* __restrict__ src, const int* __restrict__ dst,
    int* __restrict__ cursor, int* __restrict__ csr_src, int n_edges)
{
    int e = blockIdx.x * 256 + threadIdx.x;
    if (e < n_edges) {
        int d = dst[e];
        int pos = atomicAdd(&cursor[d], 1);
        csr_src[pos] = src[e];
    }
}

// ---------------- fused per-node gather: softmax + weighted sum --------
// one wave per node; FOUR edges in flight (16 lanes/edge, 4 dims/lane, bf16)
__global__ __launch_bounds__(256) void node_gather(
    const int* __restrict__ offsets, const int* __restrict__ csr_src,
    const ushort* __restrict__ qb, const ushort* __restrict__ kb,
    const ushort* __restrict__ vb, const float* __restrict__ We,
    float* __restrict__ out, int n_nodes)
{
    int node = (blockIdx.x * 256 + threadIdx.x) >> 6;
    int lane = threadIdx.x & 63;
    if (node >= n_nodes) return;
    int h   = lane & 15;     // dim group: dims 4h..4h+3
    int sub = lane >> 4;     // subgroup 0..3 -> edge slot

    int beg = offsets[node];
    int end = offsets[node + 1];

    if (beg == end) {
        if (sub == 0) {
            float4 z = make_float4(0.f, 0.f, 0.f, 0.f);
            *(float4*)&out[node * OUT_DIM + 4 * h]      = z;
            *(float4*)&out[node * OUT_DIM + 64 + 4 * h] = z;
        }
        return;
    }

    float4 kd = bf4_to_f4(*(const ushort4*)&kb[node * HID + 4 * h]);
    float4 we = *(const float4*)&We[4 * h];

    float4 o0 = make_float4(0.f, 0.f, 0.f, 0.f);
    float4 o1 = make_float4(0.f, 0.f, 0.f, 0.f);
    float ssum = 0.f;

    for (int p0 = beg; p0 < end; p0 += 4) {
        int p = p0 + sub;
        bool act = (p < end);
        int sN = csr_src[act ? p : beg];
        float4 qv = bf4_to_f4(*(const ushort4*)&qb[sN * HID + 4 * h]);
        float t;
        t  = we.x * __fdividef(1.f, 1.f + __expf(-(qv.x + kd.x)));
        t += we.y * __fdividef(1.f, 1.f + __expf(-(qv.y + kd.y)));
        t += we.z * __fdividef(1.f, 1.f + __expf(-(qv.z + kd.z)));
        t += we.w * __fdividef(1.f, 1.f + __expf(-(qv.w + kd.w)));
        t += __shfl_xor(t, 1);
        t += __shfl_xor(t, 2);
        t += __shfl_xor(t, 4);
        t += __shfl_xor(t, 8);
        float exv = act ? __expf(t) : 0.f;
        ssum += exv;
        float4 v0 = bf4_to_f4(*(const ushort4*)&vb[sN * OUT_DIM + 4 * h]);
        float4 v1 = bf4_to_f4(*(const ushort4*)&vb[sN * OUT_DIM + 64 + 4 * h]);
        o0.x += exv * v0.x; o0.y += exv * v0.y;
        o0.z += exv * v0.z; o0.w += exv * v0.w;
        o1.x += exv * v1.x; o1.y += exv * v1.y;
        o1.z += exv * v1.z; o1.w += exv * v1.w;
    }

    // combine the 4 subgroups (lanes h, h+16, h+32, h+48)
    ssum += __shfl_xor(ssum, 16); ssum += __shfl_xor(ssum, 32);
    o0.x += __shfl_xor(o0.x, 16); o0.x += __shfl_xor(o0.x, 32);
    o0.y += __shfl_xor(o0.y, 16); o0.y += __shfl_xor(o0.y, 32);
    o0.z += __shfl_xor(o0.z, 16); o0.z += __shfl_xor(o0.z, 32);
    o0.w += __shfl_xor(o0.w, 16); o0.w += __shfl_xor(o0.w, 32);
    o1.x += __shfl_xor(o1.x, 16); o1.x += __shfl_xor(o1.x, 32);
    o1.y += __shfl_xor(o1.y, 16); o1.y += __shfl_xor(o1.y, 32);
    o1.z += __shfl_xor(o1.z, 16); o1.z += __shfl_xor(o1.z, 32);
    o1.w += __shfl_xor(o1.w, 16); o1.w += __shfl_xor(o1.w, 32);

    if (sub == 0) {
        float inv = (ssum > 0.f) ? __fdividef(1.f, ssum) : 0.f;
        o0.x *= inv; o0.y *= inv; o0.z *= inv; o0.w *= inv;
        o1.x *= inv; o1.y *= inv; o1.z *= inv; o1.w *= inv;
        *(float4*)&out[node * OUT_DIM + 4 * h]      = o0;
        *(float4*)&out[node * OUT_DIM + 64 + 4 * h] = o1;
    }
}

extern "C" void kernel_launch(void* const* d_in, const int* in_sizes, int n_in,
                              void* d_out, int out_size, void* d_ws, size_t ws_size,
                              hipStream_t stream)
{
    const float* feat  = (const float*)d_in[0];
    const int*   src   = (const int*)d_in[1];
    const int*   dst   = (const int*)d_in[2];
    const float* gamma = (const float*)d_in[3];
    const float* beta  = (const float*)d_in[4];
    const float* Wq    = (const float*)d_in[5];
    const float* bq    = (const float*)d_in[6];
    const float* Wk    = (const float*)d_in[7];
    const float* Wv    = (const float*)d_in[8];
    const float* We    = (const float*)d_in[9];

    int n_nodes = in_sizes[0] / IN_DIM;
    int n_edges = in_sizes[1];

    float* ws      = (float*)d_ws;
    float* scale   = ws + 256;
    float* shift   = ws + 384;
    int*   deg     = (int*)(ws + 512);
    int*   offsets = deg + n_nodes;
    int*   cursor  = offsets + n_nodes + 1;
    int*   part    = cursor + n_nodes;
    int*   csr_src = part + SCAN_B;
    size_t bf_off  = (size_t)512 + 3 * (size_t)n_nodes + 1 + SCAN_B + (size_t)n_edges;
    bf_off = (bf_off + 3) & ~(size_t)3;     // 16B-align
    ushort* qb = (ushort*)(ws + bf_off);
    ushort* kb = qb + (size_t)n_nodes * HID;
    ushort* vb = kb + (size_t)n_nodes * HID;

    // zero stats + deg histogram (contiguous region)
    hipMemsetAsync(ws, 0, (512 + (size_t)n_nodes) * sizeof(float), stream);

    stats_kernel<<<256, 256, 0, stream>>>(feat, ws, n_nodes);
    finalize_stats<<<1, 128, 0, stream>>>(gamma, beta, ws, n_nodes);

    qkv_gemm<<<(n_nodes + 63) / 64, 256, 0, stream>>>(
        feat, Wq, bq, Wk, Wv, scale, shift, qb, kb, vb, n_nodes);

    int eb = (n_edges + 255) / 256;
    hist_kernel<<<eb, 256, 0, stream>>>(dst, deg, n_edges);
    scan_partial<<<SCAN_B, 256, 0, stream>>>(deg, part, n_nodes);
    scan_combine<<<1, 256, 0, stream>>>(part, offsets, n_nodes);
    scan_final<<<SCAN_B, 256, 0, stream>>>(deg, part, offsets, cursor, n_nodes);
    fill_kernel<<<eb, 256, 0, stream>>>(src, dst, cursor, csr_src, n_edges);

    long long g_threads = (long long)n_nodes * 64;
    node_gather<<<(int)((g_threads + 255) / 256), 256, 0, stream>>>(
        offsets, csr_src, qb, kb, vb, We, (float*)d_out, n_nodes);
}

// Round 5
// 547.153 us; speedup vs baseline: 5.6245x; 1.2093x over previous
//
#include <hip/hip_runtime.h>
#include <math.h>

#define IN_DIM 128
#define HID 64
#define OUT_DIM 128
constexpr float EPS = 1e-5f;

typedef short short8 __attribute__((ext_vector_type(8)));
typedef float f32x4  __attribute__((ext_vector_type(4)));

// ---------------------------------------------------------------------------
// ws layout:
//   float [0,128)   column sums
//   float [128,256) column sum-of-squares
//   float [256,384) scale = gamma*rsqrt(var+eps)
//   float [384,512) shift = beta - mean*scale
//   int   deg[N], offsets[N+1], cursor[N], part[256], csr_src[E]
//   bf16  qb[(N+64)*64], kb[(N+64)*64], vb[(N+64)*128]   (16B-aligned)
//   bf16  Bfrag[64*64*8]  (fragment-ordered [Wq|Wk|Wv])
// ---------------------------------------------------------------------------

__device__ inline ushort f2bf(float x) {          // RNE float->bf16 bits
    __bf16 h = (__bf16)x;
    return *reinterpret_cast<ushort*>(&h);
}
__device__ inline short f2bfs(float x) {
    __bf16 h = (__bf16)x;
    return *reinterpret_cast<short*>(&h);
}
__device__ inline float bf2f(ushort u) {
    union { unsigned u; float f; } c; c.u = ((unsigned)u) << 16;
    return c.f;
}
__device__ inline float4 bf4_to_f4(ushort4 u) {
    return make_float4(bf2f(u.x), bf2f(u.y), bf2f(u.z), bf2f(u.w));
}

__global__ __launch_bounds__(256) void stats_kernel(
    const float* __restrict__ feat, float* __restrict__ ws, int n_nodes)
{
    int col  = threadIdx.x & 127;
    int half = threadIdx.x >> 7;
    float sum = 0.f, sq = 0.f;
    for (int r = blockIdx.x * 2 + half; r < n_nodes; r += gridDim.x * 2) {
        float x = feat[r * IN_DIM + col];
        sum += x; sq += x * x;
    }
    __shared__ float redS[256], redQ[256];
    redS[threadIdx.x] = sum; redQ[threadIdx.x] = sq;
    __syncthreads();
    if (threadIdx.x < 128) {
        sum = redS[threadIdx.x] + redS[threadIdx.x + 128];
        sq  = redQ[threadIdx.x] + redQ[threadIdx.x + 128];
        unsafeAtomicAdd(&ws[col], sum);
        unsafeAtomicAdd(&ws[128 + col], sq);
    }
}

__global__ void finalize_stats(
    const float* __restrict__ gamma, const float* __restrict__ beta,
    float* __restrict__ ws, int n_nodes)
{
    int j = threadIdx.x;  // 128 threads
    float inv_n = 1.0f / (float)n_nodes;
    float mean = ws[j] * inv_n;
    float var  = ws[128 + j] * inv_n - mean * mean;
    float sc   = gamma[j] * rsqrtf(var + EPS);
    ws[256 + j] = sc;
    ws[384 + j] = beta[j] - mean * sc;
}

// One-time: lay out bf16([Wq|Wk|Wv]) in MFMA B-fragment order.
// frag id f = w*16 + ct*4 + kc  (w: wave col-slice, ct: 16-col tile, kc: 32-k chunk)
// element j of lane: B[kc*32 + (lane>>4)*8 + j][w*64 + ct*16 + (lane&15)]
__global__ __launch_bounds__(256) void wprep(
    const float* __restrict__ Wq, const float* __restrict__ Wk,
    const float* __restrict__ Wv, ushort* __restrict__ Bfrag)
{
    int gid  = blockIdx.x * 256 + threadIdx.x;   // 0..4095
    int f    = gid >> 6;
    int lane = gid & 63;
    int kc = f & 3, ct = (f >> 2) & 3, w = f >> 4;
    int col   = w * 64 + ct * 16 + (lane & 15);
    int kbase = kc * 32 + (lane >> 4) * 8;
    ushort tmp[8];
    #pragma unroll
    for (int j = 0; j < 8; j++) {
        int k = kbase + j;
        float val;
        if (col < 64)       val = Wq[k * HID + col];
        else if (col < 128) val = Wk[k * HID + (col - 64)];
        else                val = Wv[k * OUT_DIM + (col - 128)];
        tmp[j] = f2bf(val);
    }
    ushort* d = &Bfrag[(f * 64 + lane) * 8];
    *(ushort4*)d       = make_ushort4(tmp[0], tmp[1], tmp[2], tmp[3]);
    *(ushort4*)(d + 4) = make_ushort4(tmp[4], tmp[5], tmp[6], tmp[7]);
}

// MFMA layernorm+GEMM: block = 64 rows x 256 cols, wave w = 64-col slice.
// No LDS, no barriers. A-frags built in registers from fp32 feat (+ln, ->bf16).
__global__ __launch_bounds__(256) void mfma_qkv(
    const float* __restrict__ feat, const ushort* __restrict__ Bfrag,
    const float* __restrict__ bq,
    const float* __restrict__ scale, const float* __restrict__ shift,
    ushort* __restrict__ qb, ushort* __restrict__ kb, ushort* __restrict__ vb,
    int n_nodes)
{
    int w    = threadIdx.x >> 6;
    int lane = threadIdx.x & 63;
    int row0 = blockIdx.x * 64;
    int m    = lane & 15;
    int quad = lane >> 4;
    int nm1  = n_nodes - 1;

    // B fragments for this wave's 64-col slice (held in VGPRs throughout)
    short8 bfr[16];
    #pragma unroll
    for (int f = 0; f < 16; f++)
        bfr[f] = *(const short8*)&Bfrag[((w * 16 + f) * 64 + lane) * 8];

    f32x4 acc[4][4] = {};   // [row-tile][col-tile]

    #pragma unroll
    for (int kc = 0; kc < 4; kc++) {
        int koff = kc * 32 + quad * 8;
        float4 sc0 = *(const float4*)&scale[koff];
        float4 sc1 = *(const float4*)&scale[koff + 4];
        float4 sh0 = *(const float4*)&shift[koff];
        float4 sh1 = *(const float4*)&shift[koff + 4];
        short8 afr[4];
        #pragma unroll
        for (int rt = 0; rt < 4; rt++) {
            int row = row0 + rt * 16 + m;
            row = row < nm1 ? row : nm1;            // clamp OOB reads
            const float* fp = &feat[(size_t)row * IN_DIM + koff];
            float4 x0 = *(const float4*)fp;
            float4 x1 = *(const float4*)(fp + 4);
            afr[rt][0] = f2bfs(x0.x * sc0.x + sh0.x);
            afr[rt][1] = f2bfs(x0.y * sc0.y + sh0.y);
            afr[rt][2] = f2bfs(x0.z * sc0.z + sh0.z);
            afr[rt][3] = f2bfs(x0.w * sc0.w + sh0.w);
            afr[rt][4] = f2bfs(x1.x * sc1.x + sh1.x);
            afr[rt][5] = f2bfs(x1.y * sc1.y + sh1.y);
            afr[rt][6] = f2bfs(x1.z * sc1.z + sh1.z);
            afr[rt][7] = f2bfs(x1.w * sc1.w + sh1.w);
        }
        #pragma unroll
        for (int rt = 0; rt < 4; rt++)
            #pragma unroll
            for (int ct = 0; ct < 4; ct++)
                acc[rt][ct] = __builtin_amdgcn_mfma_f32_16x16x32_bf16(
                    afr[rt], bfr[ct * 4 + kc], acc[rt][ct], 0, 0, 0);
    }

    // epilogue: D[row=quad*4+r][col=m] per 16x16 tile; allocations padded
    // by 64 rows so stores are branchless.
    ushort* base; int ld, cl;
    if (w == 0)      { base = qb; ld = HID;     cl = 0; }
    else if (w == 1) { base = kb; ld = HID;     cl = 0; }
    else             { base = vb; ld = OUT_DIM; cl = (w - 2) * 64; }

    #pragma unroll
    for (int ct = 0; ct < 4; ct++) {
        int col = cl + ct * 16 + m;
        float bias = (w == 0) ? bq[ct * 16 + m] : 0.f;
        #pragma unroll
        for (int rt = 0; rt < 4; rt++) {
            int r0 = row0 + rt * 16 + quad * 4;
            #pragma unroll
            for (int r = 0; r < 4; r++)
                base[(size_t)(r0 + r) * ld + col] = f2bf(acc[rt][ct][r] + bias);
        }
    }
}

// ---------------- CSR build: histogram -> hierarchical scan -> fill ----

__global__ __launch_bounds__(256) void hist_kernel(
    const int* __restrict__ dst, int* __restrict__ deg, int n_edges)
{
    int e = blockIdx.x * 256 + threadIdx.x;
    if (e < n_edges) atomicAdd(&deg[dst[e]], 1);
}

#define SCAN_B 256

__global__ __launch_bounds__(256) void scan_partial(
    const int* __restrict__ deg, int* __restrict__ part, int n)
{
    int chunk = (n + SCAN_B - 1) / SCAN_B;
    int lo = blockIdx.x * chunk;
    int hi = lo + chunk; if (hi > n) hi = n;
    int s = 0;
    for (int i = lo + threadIdx.x; i < hi; i += 256) s += deg[i];
    __shared__ int red[256];
    red[threadIdx.x] = s; __syncthreads();
    for (int d = 128; d; d >>= 1) {
        if (threadIdx.x < d) red[threadIdx.x] += red[threadIdx.x + d];
        __syncthreads();
    }
    if (threadIdx.x == 0) part[blockIdx.x] = red[0];
}

__global__ __launch_bounds__(256) void scan_combine(
    int* __restrict__ part, int* __restrict__ offsets, int n)
{
    __shared__ int tmp[256];
    int t = threadIdx.x;
    int v = part[t];
    tmp[t] = v; __syncthreads();
    for (int d = 1; d < 256; d <<= 1) {
        int cur = tmp[t];
        int add = (t >= d) ? tmp[t - d] : 0;
        __syncthreads();
        tmp[t] = cur + add;
        __syncthreads();
    }
    part[t] = tmp[t] - v;                  // exclusive
    if (t == 255) offsets[n] = tmp[255];
}

__global__ __launch_bounds__(256) void scan_final(
    const int* __restrict__ deg, const int* __restrict__ part,
    int* __restrict__ offsets, int* __restrict__ cursor, int n)
{
    __shared__ int tmp[256];
    int t = threadIdx.x;
    int chunk = (n + SCAN_B - 1) / SCAN_B;
    int lo = blockIdx.x * chunk;
    int hi = lo + chunk; if (hi > n) hi = n;
    int base = part[blockIdx.x];
    for (int i0 = lo; i0 < hi; i0 += 256) {
        int i = i0 + t;
        int d = (i < hi) ? deg[i] : 0;
        tmp[t] = d; __syncthreads();
        for (int s = 1; s < 256; s <<= 1) {
            int cur = tmp[t];
            int add = (t >= s) ? tmp[t - s] : 0;
            __syncthreads();
            tmp[t] = cur + add;
            __syncthreads();
        }
        int excl = tmp[t] - d;
        int total = tmp[255];
        if (i < hi) { offsets[i] = base + excl; cursor[i] = base + excl; }
        base += total;
        __syncthreads();
    }
}

__global__ __launch_bounds__(256) void fill_kernel(
    const int* __restrict__ src, const int* __restrict__ dst,
    int* __restrict__ cursor, int* __restrict__ csr_src, int n_edges)
{
    int e = blockIdx.x * 256 + threadIdx.x;
    if (e < n_edges) {
        int d = dst[e];
        int pos = atomicAdd(&cursor[d], 1);
        csr_src[pos] = src[e];
    }
}

// ---------------- fused per-node gather: softmax + weighted sum --------
// one wave per node; FOUR edges in flight (16 lanes/edge, 4 dims/lane, bf16)
__global__ __launch_bounds__(256) void node_gather(
    const int* __restrict__ offsets, const int* __restrict__ csr_src,
    const ushort* __restrict__ qb, const ushort* __restrict__ kb,
    const ushort* __restrict__ vb, const float* __restrict__ We,
    float* __restrict__ out, int n_nodes)
{
    int node = (blockIdx.x * 256 + threadIdx.x) >> 6;
    int lane = threadIdx.x & 63;
    if (node >= n_nodes) return;
    int h   = lane & 15;     // dim group: dims 4h..4h+3
    int sub = lane >> 4;     // subgroup 0..3 -> edge slot

    int beg = offsets[node];
    int end = offsets[node + 1];

    if (beg == end) {
        if (sub == 0) {
            float4 z = make_float4(0.f, 0.f, 0.f, 0.f);
            *(float4*)&out[node * OUT_DIM + 4 * h]      = z;
            *(float4*)&out[node * OUT_DIM + 64 + 4 * h] = z;
        }
        return;
    }

    float4 kd = bf4_to_f4(*(const ushort4*)&kb[node * HID + 4 * h]);
    float4 we = *(const float4*)&We[4 * h];

    float4 o0 = make_float4(0.f, 0.f, 0.f, 0.f);
    float4 o1 = make_float4(0.f, 0.f, 0.f, 0.f);
    float ssum = 0.f;

    for (int p0 = beg; p0 < end; p0 += 4) {
        int p = p0 + sub;
        bool act = (p < end);
        int sN = csr_src[act ? p : beg];
        float4 qv = bf4_to_f4(*(const ushort4*)&qb[sN * HID + 4 * h]);
        float t;
        t  = we.x * __fdividef(1.f, 1.f + __expf(-(qv.x + kd.x)));
        t += we.y * __fdividef(1.f, 1.f + __expf(-(qv.y + kd.y)));
        t += we.z * __fdividef(1.f, 1.f + __expf(-(qv.z + kd.z)));
        t += we.w * __fdividef(1.f, 1.f + __expf(-(qv.w + kd.w)));
        t += __shfl_xor(t, 1);
        t += __shfl_xor(t, 2);
        t += __shfl_xor(t, 4);
        t += __shfl_xor(t, 8);
        float exv = act ? __expf(t) : 0.f;
        ssum += exv;
        float4 v0 = bf4_to_f4(*(const ushort4*)&vb[sN * OUT_DIM + 4 * h]);
        float4 v1 = bf4_to_f4(*(const ushort4*)&vb[sN * OUT_DIM + 64 + 4 * h]);
        o0.x += exv * v0.x; o0.y += exv * v0.y;
        o0.z += exv * v0.z; o0.w += exv * v0.w;
        o1.x += exv * v1.x; o1.y += exv * v1.y;
        o1.z += exv * v1.z; o1.w += exv * v1.w;
    }

    // combine the 4 subgroups (lanes h, h+16, h+32, h+48)
    ssum += __shfl_xor(ssum, 16); ssum += __shfl_xor(ssum, 32);
    o0.x += __shfl_xor(o0.x, 16); o0.x += __shfl_xor(o0.x, 32);
    o0.y += __shfl_xor(o0.y, 16); o0.y += __shfl_xor(o0.y, 32);
    o0.z += __shfl_xor(o0.z, 16); o0.z += __shfl_xor(o0.z, 32);
    o0.w += __shfl_xor(o0.w, 16); o0.w += __shfl_xor(o0.w, 32);
    o1.x += __shfl_xor(o1.x, 16); o1.x += __shfl_xor(o1.x, 32);
    o1.y += __shfl_xor(o1.y, 16); o1.y += __shfl_xor(o1.y, 32);
    o1.z += __shfl_xor(o1.z, 16); o1.z += __shfl_xor(o1.z, 32);
    o1.w += __shfl_xor(o1.w, 16); o1.w += __shfl_xor(o1.w, 32);

    if (sub == 0) {
        float inv = (ssum > 0.f) ? __fdividef(1.f, ssum) : 0.f;
        o0.x *= inv; o0.y *= inv; o0.z *= inv; o0.w *= inv;
        o1.x *= inv; o1.y *= inv; o1.z *= inv; o1.w *= inv;
        *(float4*)&out[node * OUT_DIM + 4 * h]      = o0;
        *(float4*)&out[node * OUT_DIM + 64 + 4 * h] = o1;
    }
}

extern "C" void kernel_launch(void* const* d_in, const int* in_sizes, int n_in,
                              void* d_out, int out_size, void* d_ws, size_t ws_size,
                              hipStream_t stream)
{
    const float* feat  = (const float*)d_in[0];
    const int*   src   = (const int*)d_in[1];
    const int*   dst   = (const int*)d_in[2];
    const float* gamma = (const float*)d_in[3];
    const float* beta  = (const float*)d_in[4];
    const float* Wq    = (const float*)d_in[5];
    const float* bq    = (const float*)d_in[6];
    const float* Wk    = (const float*)d_in[7];
    const float* Wv    = (const float*)d_in[8];
    const float* We    = (const float*)d_in[9];

    int n_nodes = in_sizes[0] / IN_DIM;
    int n_edges = in_sizes[1];
    int n_pad   = n_nodes + 64;             // store slack for branchless epilogue

    float* ws      = (float*)d_ws;
    float* scale   = ws + 256;
    float* shift   = ws + 384;
    int*   deg     = (int*)(ws + 512);
    int*   offsets = deg + n_nodes;
    int*   cursor  = offsets + n_nodes + 1;
    int*   part    = cursor + n_nodes;
    int*   csr_src = part + SCAN_B;
    size_t bf_off  = (size_t)512 + 3 * (size_t)n_nodes + 1 + SCAN_B + (size_t)n_edges;
    bf_off = (bf_off + 3) & ~(size_t)3;     // 16B-align
    ushort* qb    = (ushort*)(ws + bf_off);
    ushort* kb    = qb + (size_t)n_pad * HID;
    ushort* vb    = kb + (size_t)n_pad * HID;
    ushort* Bfrag = vb + (size_t)n_pad * OUT_DIM;   // 64*64*8 = 32768 ushort

    // zero stats + deg histogram (contiguous region)
    hipMemsetAsync(ws, 0, (512 + (size_t)n_nodes) * sizeof(float), stream);

    stats_kernel<<<256, 256, 0, stream>>>(feat, ws, n_nodes);
    finalize_stats<<<1, 128, 0, stream>>>(gamma, beta, ws, n_nodes);
    wprep<<<16, 256, 0, stream>>>(Wq, Wk, Wv, Bfrag);

    mfma_qkv<<<(n_nodes + 63) / 64, 256, 0, stream>>>(
        feat, Bfrag, bq, scale, shift, qb, kb, vb, n_nodes);

    int eb = (n_edges + 255) / 256;
    hist_kernel<<<eb, 256, 0, stream>>>(dst, deg, n_edges);
    scan_partial<<<SCAN_B, 256, 0, stream>>>(deg, part, n_nodes);
    scan_combine<<<1, 256, 0, stream>>>(part, offsets, n_nodes);
    scan_final<<<SCAN_B, 256, 0, stream>>>(deg, part, offsets, cursor, n_nodes);
    fill_kernel<<<eb, 256, 0, stream>>>(src, dst, cursor, csr_src, n_edges);

    long long g_threads = (long long)n_nodes * 64;
    node_gather<<<(int)((g_threads + 255) / 256), 256, 0, stream>>>(
        offsets, csr_src, qb, kb, vb, We, (float*)d_out, n_nodes);
}

// Round 6
// 430.420 us; speedup vs baseline: 7.1499x; 1.2712x over previous
//
#include <hip/hip_runtime.h>
#include <math.h>

#define IN_DIM 128
#define HID 64
#define OUT_DIM 128
#define ELL_W 64
constexpr float EPS = 1e-5f;

typedef short short8 __attribute__((ext_vector_type(8)));
typedef float f32x4  __attribute__((ext_vector_type(4)));

// ---------------------------------------------------------------------------
// ws layout (ELL path):
//   float [0,128)   column sums        float [128,256) column sum-of-squares
//   int   deg[N], ell[N*64]
//   bf16  qb[(N+64)*64], kb[(N+64)*64], vb[(N+64)*128]   (16B-aligned)
//   bf16  Bfrag[64*64*8]
// Fallback (CSR) path replaces deg/ell with deg/offsets/cursor/part/csr_src.
// ---------------------------------------------------------------------------

__device__ inline ushort f2bf(float x) {          // RNE float->bf16 bits
    __bf16 h = (__bf16)x;
    return *reinterpret_cast<ushort*>(&h);
}
__device__ inline short f2bfs(float x) {
    __bf16 h = (__bf16)x;
    return *reinterpret_cast<short*>(&h);
}
__device__ inline float bf2f(ushort u) {
    union { unsigned u; float f; } c; c.u = ((unsigned)u) << 16;
    return c.f;
}
__device__ inline float4 bf4_to_f4(ushort4 u) {
    return make_float4(bf2f(u.x), bf2f(u.y), bf2f(u.z), bf2f(u.w));
}

__global__ __launch_bounds__(256) void stats_kernel(
    const float* __restrict__ feat, float* __restrict__ ws, int n_nodes)
{
    int col  = threadIdx.x & 127;
    int half = threadIdx.x >> 7;
    float sum = 0.f, sq = 0.f;
    for (int r = blockIdx.x * 2 + half; r < n_nodes; r += gridDim.x * 2) {
        float x = feat[r * IN_DIM + col];
        sum += x; sq += x * x;
    }
    __shared__ float redS[256], redQ[256];
    redS[threadIdx.x] = sum; redQ[threadIdx.x] = sq;
    __syncthreads();
    if (threadIdx.x < 128) {
        sum = redS[threadIdx.x] + redS[threadIdx.x + 128];
        sq  = redQ[threadIdx.x] + redQ[threadIdx.x + 128];
        unsafeAtomicAdd(&ws[col], sum);
        unsafeAtomicAdd(&ws[128 + col], sq);
    }
}

// One-time: lay out bf16([Wq|Wk|Wv]) in MFMA B-fragment order.
__global__ __launch_bounds__(256) void wprep(
    const float* __restrict__ Wq, const float* __restrict__ Wk,
    const float* __restrict__ Wv, ushort* __restrict__ Bfrag)
{
    int gid  = blockIdx.x * 256 + threadIdx.x;   // 0..4095
    int f    = gid >> 6;
    int lane = gid & 63;
    int kc = f & 3, ct = (f >> 2) & 3, w = f >> 4;
    int col   = w * 64 + ct * 16 + (lane & 15);
    int kbase = kc * 32 + (lane >> 4) * 8;
    ushort tmp[8];
    #pragma unroll
    for (int j = 0; j < 8; j++) {
        int k = kbase + j;
        float val;
        if (col < 64)       val = Wq[k * HID + col];
        else if (col < 128) val = Wk[k * HID + (col - 64)];
        else                val = Wv[k * OUT_DIM + (col - 128)];
        tmp[j] = f2bf(val);
    }
    ushort* d = &Bfrag[(f * 64 + lane) * 8];
    *(ushort4*)d       = make_ushort4(tmp[0], tmp[1], tmp[2], tmp[3]);
    *(ushort4*)(d + 4) = make_ushort4(tmp[4], tmp[5], tmp[6], tmp[7]);
}

// MFMA layernorm+GEMM, finalize-stats inlined (scale/shift derived per block).
__global__ __launch_bounds__(256) void mfma_qkv(
    const float* __restrict__ feat, const ushort* __restrict__ Bfrag,
    const float* __restrict__ bq,
    const float* __restrict__ gamma, const float* __restrict__ beta,
    const float* __restrict__ stats,
    ushort* __restrict__ qb, ushort* __restrict__ kb, ushort* __restrict__ vb,
    int n_nodes)
{
    __shared__ float sc[IN_DIM], sh[IN_DIM];
    int tid = threadIdx.x;
    if (tid < 128) {
        float inv_n = 1.0f / (float)n_nodes;
        float mean = stats[tid] * inv_n;
        float var  = stats[128 + tid] * inv_n - mean * mean;
        float s    = gamma[tid] * rsqrtf(var + EPS);
        sc[tid] = s; sh[tid] = beta[tid] - mean * s;
    }

    int w    = tid >> 6;
    int lane = tid & 63;
    int row0 = blockIdx.x * 64;
    int m    = lane & 15;
    int quad = lane >> 4;
    int nm1  = n_nodes - 1;

    short8 bfr[16];
    #pragma unroll
    for (int f = 0; f < 16; f++)
        bfr[f] = *(const short8*)&Bfrag[((w * 16 + f) * 64 + lane) * 8];

    __syncthreads();

    f32x4 acc[4][4] = {};   // [row-tile][col-tile]

    #pragma unroll
    for (int kc = 0; kc < 4; kc++) {
        int koff = kc * 32 + quad * 8;
        float4 sc0 = *(const float4*)&sc[koff];
        float4 sc1 = *(const float4*)&sc[koff + 4];
        float4 sh0 = *(const float4*)&sh[koff];
        float4 sh1 = *(const float4*)&sh[koff + 4];
        short8 afr[4];
        #pragma unroll
        for (int rt = 0; rt < 4; rt++) {
            int row = row0 + rt * 16 + m;
            row = row < nm1 ? row : nm1;            // clamp OOB reads
            const float* fp = &feat[(size_t)row * IN_DIM + koff];
            float4 x0 = *(const float4*)fp;
            float4 x1 = *(const float4*)(fp + 4);
            afr[rt][0] = f2bfs(x0.x * sc0.x + sh0.x);
            afr[rt][1] = f2bfs(x0.y * sc0.y + sh0.y);
            afr[rt][2] = f2bfs(x0.z * sc0.z + sh0.z);
            afr[rt][3] = f2bfs(x0.w * sc0.w + sh0.w);
            afr[rt][4] = f2bfs(x1.x * sc1.x + sh1.x);
            afr[rt][5] = f2bfs(x1.y * sc1.y + sh1.y);
            afr[rt][6] = f2bfs(x1.z * sc1.z + sh1.z);
            afr[rt][7] = f2bfs(x1.w * sc1.w + sh1.w);
        }
        #pragma unroll
        for (int rt = 0; rt < 4; rt++)
            #pragma unroll
            for (int ct = 0; ct < 4; ct++)
                acc[rt][ct] = __builtin_amdgcn_mfma_f32_16x16x32_bf16(
                    afr[rt], bfr[ct * 4 + kc], acc[rt][ct], 0, 0, 0);
    }

    ushort* base; int ld, cl;
    if (w == 0)      { base = qb; ld = HID;     cl = 0; }
    else if (w == 1) { base = kb; ld = HID;     cl = 0; }
    else             { base = vb; ld = OUT_DIM; cl = (w - 2) * 64; }

    #pragma unroll
    for (int ct = 0; ct < 4; ct++) {
        int col = cl + ct * 16 + m;
        float bias = (w == 0) ? bq[ct * 16 + m] : 0.f;
        #pragma unroll
        for (int rt = 0; rt < 4; rt++) {
            int r0 = row0 + rt * 16 + quad * 4;
            #pragma unroll
            for (int r = 0; r < 4; r++)
                base[(size_t)(r0 + r) * ld + col] = f2bf(acc[rt][ct][r] + bias);
        }
    }
}

// ---------------- ELL build: one pass, no hist/scan --------------------
__global__ __launch_bounds__(256) void fill_ell(
    const int* __restrict__ src, const int* __restrict__ dst,
    int* __restrict__ deg, int* __restrict__ ell, int n_edges)
{
    int stride = gridDim.x * 256;
    for (int e = blockIdx.x * 256 + threadIdx.x; e < n_edges; e += stride) {
        int d = dst[e];
        int s = src[e];
        int pos = atomicAdd(&deg[d], 1);
        if (pos < ELL_W) ell[d * ELL_W + pos] = s;
    }
}

// ---------------- CSR fallback kernels (used if ws too small) ----------
__global__ __launch_bounds__(256) void hist_kernel(
    const int* __restrict__ dst, int* __restrict__ deg, int n_edges)
{
    int e = blockIdx.x * 256 + threadIdx.x;
    if (e < n_edges) atomicAdd(&deg[dst[e]], 1);
}

#define SCAN_B 256

__global__ __launch_bounds__(256) void scan_partial(
    const int* __restrict__ deg, int* __restrict__ part, int n)
{
    int chunk = (n + SCAN_B - 1) / SCAN_B;
    int lo = blockIdx.x * chunk;
    int hi = lo + chunk; if (hi > n) hi = n;
    int s = 0;
    for (int i = lo + threadIdx.x; i < hi; i += 256) s += deg[i];
    __shared__ int red[256];
    red[threadIdx.x] = s; __syncthreads();
    for (int d = 128; d; d >>= 1) {
        if (threadIdx.x < d) red[threadIdx.x] += red[threadIdx.x + d];
        __syncthreads();
    }
    if (threadIdx.x == 0) part[blockIdx.x] = red[0];
}

__global__ __launch_bounds__(256) void scan_combine(
    int* __restrict__ part, int* __restrict__ offsets, int n)
{
    __shared__ int tmp[256];
    int t = threadIdx.x;
    int v = part[t];
    tmp[t] = v; __syncthreads();
    for (int d = 1; d < 256; d <<= 1) {
        int cur = tmp[t];
        int add = (t >= d) ? tmp[t - d] : 0;
        __syncthreads();
        tmp[t] = cur + add;
        __syncthreads();
    }
    part[t] = tmp[t] - v;
    if (t == 255) offsets[n] = tmp[255];
}

__global__ __launch_bounds__(256) void scan_final(
    const int* __restrict__ deg, const int* __restrict__ part,
    int* __restrict__ offsets, int* __restrict__ cursor, int n)
{
    __shared__ int tmp[256];
    int t = threadIdx.x;
    int chunk = (n + SCAN_B - 1) / SCAN_B;
    int lo = blockIdx.x * chunk;
    int hi = lo + chunk; if (hi > n) hi = n;
    int base = part[blockIdx.x];
    for (int i0 = lo; i0 < hi; i0 += 256) {
        int i = i0 + t;
        int d = (i < hi) ? deg[i] : 0;
        tmp[t] = d; __syncthreads();
        for (int s = 1; s < 256; s <<= 1) {
            int cur = tmp[t];
            int add = (t >= s) ? tmp[t - s] : 0;
            __syncthreads();
            tmp[t] = cur + add;
            __syncthreads();
        }
        int excl = tmp[t] - d;
        int total = tmp[255];
        if (i < hi) { offsets[i] = base + excl; cursor[i] = base + excl; }
        base += total;
        __syncthreads();
    }
}

__global__ __launch_bounds__(256) void fill_kernel(
    const int* __restrict__ src, const int* __restrict__ dst,
    int* __restrict__ cursor, int* __restrict__ csr_src, int n_edges)
{
    int e = blockIdx.x * 256 + threadIdx.x;
    if (e < n_edges) {
        int d = dst[e];
        int pos = atomicAdd(&cursor[d], 1);
        csr_src[pos] = src[e];
    }
}

// ---------------- fused per-node gather core ---------------------------
__device__ inline void gather_core(
    const int* __restrict__ row, int cnt, int node, int h, int sub,
    const ushort* __restrict__ qb, const ushort* __restrict__ kb,
    const ushort* __restrict__ vb, const float* __restrict__ We,
    float* __restrict__ out)
{
    if (cnt == 0) {
        if (sub == 0) {
            float4 z = make_float4(0.f, 0.f, 0.f, 0.f);
            *(float4*)&out[node * OUT_DIM + 4 * h]      = z;
            *(float4*)&out[node * OUT_DIM + 64 + 4 * h] = z;
        }
        return;
    }

    float4 kd = bf4_to_f4(*(const ushort4*)&kb[node * HID + 4 * h]);
    float4 we = *(const float4*)&We[4 * h];

    float4 o0 = make_float4(0.f, 0.f, 0.f, 0.f);
    float4 o1 = make_float4(0.f, 0.f, 0.f, 0.f);
    float ssum = 0.f;

    for (int p0 = 0; p0 < cnt; p0 += 4) {
        int p = p0 + sub;
        bool act = (p < cnt);
        int sN = row[act ? p : 0];
        float4 qv = bf4_to_f4(*(const ushort4*)&qb[sN * HID + 4 * h]);
        float t;
        t  = we.x * __fdividef(1.f, 1.f + __expf(-(qv.x + kd.x)));
        t += we.y * __fdividef(1.f, 1.f + __expf(-(qv.y + kd.y)));
        t += we.z * __fdividef(1.f, 1.f + __expf(-(qv.z + kd.z)));
        t += we.w * __fdividef(1.f, 1.f + __expf(-(qv.w + kd.w)));
        t += __shfl_xor(t, 1);
        t += __shfl_xor(t, 2);
        t += __shfl_xor(t, 4);
        t += __shfl_xor(t, 8);
        float exv = act ? __expf(t) : 0.f;
        ssum += exv;
        float4 v0 = bf4_to_f4(*(const ushort4*)&vb[sN * OUT_DIM + 4 * h]);
        float4 v1 = bf4_to_f4(*(const ushort4*)&vb[sN * OUT_DIM + 64 + 4 * h]);
        o0.x += exv * v0.x; o0.y += exv * v0.y;
        o0.z += exv * v0.z; o0.w += exv * v0.w;
        o1.x += exv * v1.x; o1.y += exv * v1.y;
        o1.z += exv * v1.z; o1.w += exv * v1.w;
    }

    ssum += __shfl_xor(ssum, 16); ssum += __shfl_xor(ssum, 32);
    o0.x += __shfl_xor(o0.x, 16); o0.x += __shfl_xor(o0.x, 32);
    o0.y += __shfl_xor(o0.y, 16); o0.y += __shfl_xor(o0.y, 32);
    o0.z += __shfl_xor(o0.z, 16); o0.z += __shfl_xor(o0.z, 32);
    o0.w += __shfl_xor(o0.w, 16); o0.w += __shfl_xor(o0.w, 32);
    o1.x += __shfl_xor(o1.x, 16); o1.x += __shfl_xor(o1.x, 32);
    o1.y += __shfl_xor(o1.y, 16); o1.y += __shfl_xor(o1.y, 32);
    o1.z += __shfl_xor(o1.z, 16); o1.z += __shfl_xor(o1.z, 32);
    o1.w += __shfl_xor(o1.w, 16); o1.w += __shfl_xor(o1.w, 32);

    if (sub == 0) {
        float inv = (ssum > 0.f) ? __fdividef(1.f, ssum) : 0.f;
        o0.x *= inv; o0.y *= inv; o0.z *= inv; o0.w *= inv;
        o1.x *= inv; o1.y *= inv; o1.z *= inv; o1.w *= inv;
        *(float4*)&out[node * OUT_DIM + 4 * h]      = o0;
        *(float4*)&out[node * OUT_DIM + 64 + 4 * h] = o1;
    }
}

__global__ __launch_bounds__(256) void gather_ell(
    const int* __restrict__ deg, const int* __restrict__ ell,
    const ushort* __restrict__ qb, const ushort* __restrict__ kb,
    const ushort* __restrict__ vb, const float* __restrict__ We,
    float* __restrict__ out, int n_nodes)
{
    int node = (blockIdx.x * 256 + threadIdx.x) >> 6;
    int lane = threadIdx.x & 63;
    if (node >= n_nodes) return;
    int cnt = deg[node];
    cnt = cnt < ELL_W ? cnt : ELL_W;
    gather_core(&ell[(size_t)node * ELL_W], cnt, node,
                lane & 15, lane >> 4, qb, kb, vb, We, out);
}

__global__ __launch_bounds__(256) void gather_csr(
    const int* __restrict__ offsets, const int* __restrict__ csr_src,
    const ushort* __restrict__ qb, const ushort* __restrict__ kb,
    const ushort* __restrict__ vb, const float* __restrict__ We,
    float* __restrict__ out, int n_nodes)
{
    int node = (blockIdx.x * 256 + threadIdx.x) >> 6;
    int lane = threadIdx.x & 63;
    if (node >= n_nodes) return;
    int beg = offsets[node];
    int cnt = offsets[node + 1] - beg;
    gather_core(&csr_src[beg], cnt, node,
                lane & 15, lane >> 4, qb, kb, vb, We, out);
}

extern "C" void kernel_launch(void* const* d_in, const int* in_sizes, int n_in,
                              void* d_out, int out_size, void* d_ws, size_t ws_size,
                              hipStream_t stream)
{
    const float* feat  = (const float*)d_in[0];
    const int*   src   = (const int*)d_in[1];
    const int*   dst   = (const int*)d_in[2];
    const float* gamma = (const float*)d_in[3];
    const float* beta  = (const float*)d_in[4];
    const float* Wq    = (const float*)d_in[5];
    const float* bq    = (const float*)d_in[6];
    const float* Wk    = (const float*)d_in[7];
    const float* Wv    = (const float*)d_in[8];
    const float* We    = (const float*)d_in[9];

    int n_nodes = in_sizes[0] / IN_DIM;
    int n_edges = in_sizes[1];
    int n_pad   = n_nodes + 64;             // store slack for branchless epilogue
    size_t bfelems = (size_t)n_pad * (HID + HID + OUT_DIM) + 64 * 64 * 8;

    float* ws = (float*)d_ws;

    // ELL-path workspace requirement
    size_t ell_floats = 256 + (size_t)n_nodes * (1 + ELL_W) + 4;
    size_t ell_need   = (ell_floats + (bfelems + 1) / 2) * 4;

    int eb = (n_edges + 255) / 256;

    if (ws_size >= ell_need) {
        // ---------------- ELL path: 6 dispatches ----------------
        int* deg = (int*)(ws + 256);
        int* ell = deg + n_nodes;
        size_t off = 256 + (size_t)n_nodes * (1 + ELL_W);
        off = (off + 3) & ~(size_t)3;
        ushort* qb    = (ushort*)(ws + off);
        ushort* kb    = qb + (size_t)n_pad * HID;
        ushort* vb    = kb + (size_t)n_pad * HID;
        ushort* Bfrag = vb + (size_t)n_pad * OUT_DIM;

        hipMemsetAsync(ws, 0, (256 + (size_t)n_nodes) * sizeof(float), stream);
        stats_kernel<<<256, 256, 0, stream>>>(feat, ws, n_nodes);
        wprep<<<16, 256, 0, stream>>>(Wq, Wk, Wv, Bfrag);
        fill_ell<<<(n_edges + 1023) / 1024, 256, 0, stream>>>(
            src, dst, deg, ell, n_edges);
        mfma_qkv<<<(n_nodes + 63) / 64, 256, 0, stream>>>(
            feat, Bfrag, bq, gamma, beta, ws, qb, kb, vb, n_nodes);
        long long g_threads = (long long)n_nodes * 64;
        gather_ell<<<(int)((g_threads + 255) / 256), 256, 0, stream>>>(
            deg, ell, qb, kb, vb, We, (float*)d_out, n_nodes);
    } else {
        // ---------------- CSR fallback: 10 dispatches ----------------
        int* deg     = (int*)(ws + 256);
        int* offsets = deg + n_nodes;
        int* cursor  = offsets + n_nodes + 1;
        int* part    = cursor + n_nodes;
        int* csr_src = part + SCAN_B;
        size_t off = 256 + 3 * (size_t)n_nodes + 1 + SCAN_B + (size_t)n_edges;
        off = (off + 3) & ~(size_t)3;
        ushort* qb    = (ushort*)(ws + off);
        ushort* kb    = qb + (size_t)n_pad * HID;
        ushort* vb    = kb + (size_t)n_pad * HID;
        ushort* Bfrag = vb + (size_t)n_pad * OUT_DIM;

        hipMemsetAsync(ws, 0, (256 + (size_t)n_nodes) * sizeof(float), stream);
        stats_kernel<<<256, 256, 0, stream>>>(feat, ws, n_nodes);
        wprep<<<16, 256, 0, stream>>>(Wq, Wk, Wv, Bfrag);
        hist_kernel<<<eb, 256, 0, stream>>>(dst, deg, n_edges);
        scan_partial<<<SCAN_B, 256, 0, stream>>>(deg, part, n_nodes);
        scan_combine<<<1, 256, 0, stream>>>(part, offsets, n_nodes);
        scan_final<<<SCAN_B, 256, 0, stream>>>(deg, part, offsets, cursor, n_nodes);
        fill_kernel<<<eb, 256, 0, stream>>>(src, dst, cursor, csr_src, n_edges);
        mfma_qkv<<<(n_nodes + 63) / 64, 256, 0, stream>>>(
            feat, Bfrag, bq, gamma, beta, ws, qb, kb, vb, n_nodes);
        long long g_threads = (long long)n_nodes * 64;
        gather_csr<<<(int)((g_threads + 255) / 256), 256, 0, stream>>>(
            offsets, csr_src, qb, kb, vb, We, (float*)d_out, n_nodes);
    }
}